// Round 1
// baseline (1330.402 us; speedup 1.0000x reference)
//
#include <hip/hip_runtime.h>
#include <hip/hip_bf16.h>
#include <stdint.h>

typedef __attribute__((ext_vector_type(8))) short short8;
typedef __attribute__((ext_vector_type(4))) float f32x4;

__device__ inline unsigned short f2bf(float f) {
    union { float f; uint32_t u; } v; v.f = f;
    uint32_t u = v.u;
    uint32_t r = (u + 0x7FFFu + ((u >> 16) & 1u)) >> 16;
    return (unsigned short)r;
}

// ---------------- weight converts ----------------
__global__ void cvt_w1(const float* __restrict__ w, unsigned short* __restrict__ A1) {
    int idx = blockIdx.x * 256 + threadIdx.x;   // 65536 total
    int row = idx >> 8, k = idx & 255;
    float v = (k < 243) ? w[row * 243 + k] : 0.f;
    A1[idx] = f2bf(v);
}

__global__ void cvt_w2(const float* __restrict__ w, unsigned short* __restrict__ A2) {
    int idx = blockIdx.x * 256 + threadIdx.x;   // 5308416 total
    A2[idx] = f2bf(w[idx]);
}

// ---------------- conv1 as implicit GEMM ----------------
// C[oc, n] = sum_k A1[oc,k] * im2col(x)[k,n];  K=243 (padded 256), N=32*56*56=100352
// epilogue: relu(val + bias) -> h1 bf16 [32][256][56][56]
__global__ __launch_bounds__(256) void conv1_gemm(
    const unsigned short* __restrict__ A,   // [256][256] bf16
    const float* __restrict__ x,            // [32][3][64][64]
    const float* __restrict__ bias,         // [256]
    unsigned short* __restrict__ h1)        // [32][256][56][56] bf16
{
    __shared__ unsigned short As[128 * 40];
    __shared__ unsigned short Bs[128 * 40];
    const int tid = threadIdx.x;
    const int m0 = blockIdx.y * 128;
    const int n0 = blockIdx.x * 128;
    const int lane = tid & 63;
    const int wave = tid >> 6;
    const int wy = wave & 1, wx = wave >> 1;
    const int l16 = lane & 15, q = lane >> 4;

    const int kp = tid & 15;   // k-pair 0..15 (k = k0+2kp, +1)
    const int gn = tid >> 4;   // 0..15, covers 8 n each
    int baseN[8];
#pragma unroll
    for (int j = 0; j < 8; ++j) {
        int n = n0 + gn * 8 + j;
        int b = n / 3136, p = n % 3136;
        int oy = p / 56, ox = p % 56;
        baseN[j] = b * 12288 + oy * 64 + ox;
    }

    f32x4 acc[4][4];
#pragma unroll
    for (int im = 0; im < 4; ++im)
#pragma unroll
        for (int in = 0; in < 4; ++in)
            acc[im][in] = (f32x4){0.f, 0.f, 0.f, 0.f};

    for (int k0 = 0; k0 < 256; k0 += 32) {
        __syncthreads();
        // stage A (128x32)
#pragma unroll
        for (int s = 0; s < 2; ++s) {
            int slot = tid + s * 256;
            int row = slot >> 2, seg = slot & 3;
            uint4 v = *(const uint4*)(A + (m0 + row) * 256 + k0 + seg * 8);
            *(uint4*)(&As[row * 40 + seg * 8]) = v;
        }
        // stage B (im2col gather, 32x128 -> Bs[n][k])
        int ka = k0 + 2 * kp, kb = ka + 1;
        int offa = 0, offb = 0;
        bool va = ka < 243, vb = kb < 243;
        if (va) { int c = ka / 81, t = ka % 81, ky = t / 9, kx = t % 9; offa = c * 4096 + ky * 64 + kx; }
        if (vb) { int c = kb / 81, t = kb % 81, ky = t / 9, kx = t % 9; offb = c * 4096 + ky * 64 + kx; }
#pragma unroll
        for (int j = 0; j < 8; ++j) {
            unsigned int ba = va ? (unsigned int)f2bf(x[baseN[j] + offa]) : 0u;
            unsigned int bb = vb ? (unsigned int)f2bf(x[baseN[j] + offb]) : 0u;
            *(unsigned int*)(&Bs[(gn * 8 + j) * 40 + 2 * kp]) = ba | (bb << 16);
        }
        __syncthreads();

        short8 af[4], bf[4];
#pragma unroll
        for (int im = 0; im < 4; ++im)
            af[im] = *(const short8*)(&As[(wy * 64 + im * 16 + l16) * 40 + q * 8]);
#pragma unroll
        for (int in = 0; in < 4; ++in)
            bf[in] = *(const short8*)(&Bs[(wx * 64 + in * 16 + l16) * 40 + q * 8]);
#pragma unroll
        for (int im = 0; im < 4; ++im)
#pragma unroll
            for (int in = 0; in < 4; ++in)
                acc[im][in] = __builtin_amdgcn_mfma_f32_16x16x32_bf16(af[im], bf[in], acc[im][in], 0, 0, 0);
    }

    // epilogue: relu + bias, write bf16 h1
#pragma unroll
    for (int in = 0; in < 4; ++in) {
        int n = n0 + wx * 64 + in * 16 + l16;
        int b = n / 3136, p = n % 3136;
        int oy = p / 56, ox = p % 56;
#pragma unroll
        for (int im = 0; im < 4; ++im) {
#pragma unroll
            for (int r = 0; r < 4; ++r) {
                int oc = m0 + wy * 64 + im * 16 + q * 4 + r;
                float v = acc[im][in][r] + bias[oc];
                v = v > 0.f ? v : 0.f;
                h1[((b * 256 + oc) * 56 + oy) * 56 + ox] = f2bf(v);
            }
        }
    }
}

// ---------------- conv2 as implicit GEMM ----------------
// C[oc, n] = sum_k A2[oc,k] * im2col(h1)[k,n]; K=20736, N=32*24*24=18432, stride 2
__global__ __launch_bounds__(256) void conv2_gemm(
    const unsigned short* __restrict__ A,   // [256][20736] bf16
    const unsigned short* __restrict__ h1,  // [32][256][56][56] bf16
    const float* __restrict__ bias,         // [256]
    float* __restrict__ c2)                 // [32][256][576] fp32
{
    __shared__ unsigned short As[128 * 40];
    __shared__ unsigned short Bs[128 * 40];
    const int tid = threadIdx.x;
    const int m0 = blockIdx.y * 128;
    const int n0 = blockIdx.x * 128;
    const int lane = tid & 63;
    const int wave = tid >> 6;
    const int wy = wave & 1, wx = wave >> 1;
    const int l16 = lane & 15, q = lane >> 4;

    const int kp = tid & 15;
    const int gn = tid >> 4;
    int baseN[8];
#pragma unroll
    for (int j = 0; j < 8; ++j) {
        int n = n0 + gn * 8 + j;
        int b = n / 576, p = n % 576;
        int oy = p / 24, ox = p % 24;
        baseN[j] = b * 802816 + oy * 112 + ox * 2;
    }

    f32x4 acc[4][4];
#pragma unroll
    for (int im = 0; im < 4; ++im)
#pragma unroll
        for (int in = 0; in < 4; ++in)
            acc[im][in] = (f32x4){0.f, 0.f, 0.f, 0.f};

    for (int k0 = 0; k0 < 20736; k0 += 32) {
        __syncthreads();
#pragma unroll
        for (int s = 0; s < 2; ++s) {
            int slot = tid + s * 256;
            int row = slot >> 2, seg = slot & 3;
            uint4 v = *(const uint4*)(A + (m0 + row) * 20736 + k0 + seg * 8);
            *(uint4*)(&As[row * 40 + seg * 8]) = v;
        }
        int ka = k0 + 2 * kp, kb = ka + 1;
        int offa, offb;
        { int ic = ka / 81, t = ka % 81, ky = t / 9, kx = t % 9; offa = ic * 3136 + ky * 56 + kx; }
        { int ic = kb / 81, t = kb % 81, ky = t / 9, kx = t % 9; offb = ic * 3136 + ky * 56 + kx; }
#pragma unroll
        for (int j = 0; j < 8; ++j) {
            unsigned int ba = (unsigned int)h1[baseN[j] + offa];
            unsigned int bb = (unsigned int)h1[baseN[j] + offb];
            *(unsigned int*)(&Bs[(gn * 8 + j) * 40 + 2 * kp]) = ba | (bb << 16);
        }
        __syncthreads();

        short8 af[4], bf[4];
#pragma unroll
        for (int im = 0; im < 4; ++im)
            af[im] = *(const short8*)(&As[(wy * 64 + im * 16 + l16) * 40 + q * 8]);
#pragma unroll
        for (int in = 0; in < 4; ++in)
            bf[in] = *(const short8*)(&Bs[(wx * 64 + in * 16 + l16) * 40 + q * 8]);
#pragma unroll
        for (int im = 0; im < 4; ++im)
#pragma unroll
            for (int in = 0; in < 4; ++in)
                acc[im][in] = __builtin_amdgcn_mfma_f32_16x16x32_bf16(af[im], bf[in], acc[im][in], 0, 0, 0);
    }

#pragma unroll
    for (int in = 0; in < 4; ++in) {
        int n = n0 + wx * 64 + in * 16 + l16;
        int b = n / 576, p = n % 576;
#pragma unroll
        for (int im = 0; im < 4; ++im) {
#pragma unroll
            for (int r = 0; r < 4; ++r) {
                int oc = m0 + wy * 64 + im * 16 + q * 4 + r;
                c2[(b * 256 + oc) * 576 + p] = acc[im][in][r] + bias[oc];
            }
        }
    }
}

// ---------------- squash primary caps ----------------
// c2 [b][256][576] -> caps [b][32][576][8], squash over the 8-dim
__global__ void squash_caps(const float* __restrict__ c2, float* __restrict__ caps) {
    int idx = blockIdx.x * 256 + threadIdx.x;   // 589824 = 32*32*576
    int b = idx / 18432;
    int rp = idx % 18432;
    int r = rp / 576, p = rp % 576;
    float s[8]; float n2 = 0.f;
#pragma unroll
    for (int d = 0; d < 8; ++d) {
        s[d] = c2[(b * 256 + r * 8 + d) * 576 + p];
        n2 += s[d] * s[d];
    }
    float sc = (n2 / (1.f + n2)) / sqrtf(n2 + 1e-8f);
#pragma unroll
    for (int d = 0; d < 8; ++d)
        caps[idx * 8 + d] = sc * s[d];
}

// ---------------- routing ----------------
// Wv[b,r,c,i] = sum_o W[r,c,i,o] * V[b,c,o]
__global__ void wv_kernel(const float* __restrict__ W, const float* __restrict__ V,
                          float* __restrict__ Wv) {
    int r = blockIdx.x, b = blockIdx.y;
    int c = threadIdx.x / 8, i = threadIdx.x % 8;   // 80 threads
    float s = 0.f;
#pragma unroll
    for (int o = 0; o < 16; ++o)
        s += W[((r * 10 + c) * 8 + i) * 16 + o] * V[(b * 10 + c) * 16 + o];
    Wv[(b * 32 + r) * 80 + c * 8 + i] = s;
}

// G[b,r,c,i] = sum_p softmax_c(caps[b,r,p,:]·Wv[b,r,c,:])[c] * caps[b,r,p,i]
__global__ __launch_bounds__(64) void route_accum(const float* __restrict__ caps,
                                                  const float* __restrict__ Wv,
                                                  float* __restrict__ G) {
    int r = blockIdx.x, b = blockIdx.y;
    __shared__ float wv[80];
    __shared__ float red[80][64];
    int tid = threadIdx.x;
    for (int v = tid; v < 80; v += 64) wv[v] = Wv[(b * 32 + r) * 80 + v];
    __syncthreads();
    float g[80];
#pragma unroll
    for (int v = 0; v < 80; ++v) g[v] = 0.f;
    const float* cp = caps + (size_t)(b * 32 + r) * 576 * 8;
    for (int j = 0; j < 9; ++j) {
        int p = j * 64 + tid;
        const f32x4* qp = (const f32x4*)(cp + p * 8);
        f32x4 c0 = qp[0], c1 = qp[1];
        float c8[8];
#pragma unroll
        for (int i = 0; i < 4; ++i) { c8[i] = c0[i]; c8[4 + i] = c1[i]; }
        float a[10]; float m = -1e30f;
#pragma unroll
        for (int c = 0; c < 10; ++c) {
            float t = 0.f;
#pragma unroll
            for (int i = 0; i < 8; ++i) t += c8[i] * wv[c * 8 + i];
            a[c] = t; m = fmaxf(m, t);
        }
        float sum = 0.f;
#pragma unroll
        for (int c = 0; c < 10; ++c) { a[c] = __expf(a[c] - m); sum += a[c]; }
        float inv = 1.f / sum;
#pragma unroll
        for (int c = 0; c < 10; ++c) {
            float cc = a[c] * inv;
#pragma unroll
            for (int i = 0; i < 8; ++i) g[c * 8 + i] += cc * c8[i];
        }
    }
#pragma unroll
    for (int v = 0; v < 80; ++v) red[v][tid] = g[v];
    __syncthreads();
    for (int v = tid; v < 80; v += 64) {
        float s = 0.f;
        for (int t = 0; t < 64; ++t) s += red[v][t];
        G[(b * 32 + r) * 80 + v] = s;
    }
}

// s[b,c,o] = sum_{r,i} G[b,r,c,i]*W[r,c,i,o]; v=squash(s); V+=v; maybe write out
__global__ __launch_bounds__(160) void sv_kernel(const float* __restrict__ G,
                                                 const float* __restrict__ W,
                                                 float* __restrict__ V,
                                                 float* __restrict__ out, int last) {
    int b = blockIdx.x;
    int c = threadIdx.x / 16, o = threadIdx.x % 16;
    __shared__ float sL[10][16];
    float s = 0.f;
    for (int r = 0; r < 32; ++r) {
        const float* g = G + ((b * 32 + r) * 10 + c) * 8;
        const float* w = W + ((r * 10 + c) * 8) * 16 + o;
#pragma unroll
        for (int i = 0; i < 8; ++i) s += g[i] * w[i * 16];
    }
    sL[c][o] = s;
    __syncthreads();
    float n2 = 0.f;
#pragma unroll
    for (int oo = 0; oo < 16; ++oo) { float t = sL[c][oo]; n2 += t * t; }
    float sc = (n2 / (1.f + n2)) / sqrtf(n2 + 1e-8f);
    float v = sc * s;
    V[(b * 10 + c) * 16 + o] += v;
    if (last) out[(b * 10 + c) * 16 + o] = v;
}

// ---------------- launch ----------------
extern "C" void kernel_launch(void* const* d_in, const int* in_sizes, int n_in,
                              void* d_out, int out_size, void* d_ws, size_t ws_size,
                              hipStream_t stream) {
    const float* x  = (const float*)d_in[0];
    const float* w1 = (const float*)d_in[1];
    const float* b1 = (const float*)d_in[2];
    const float* w2 = (const float*)d_in[3];
    const float* b2 = (const float*)d_in[4];
    const float* rw = (const float*)d_in[5];

    char* ws = (char*)d_ws;
    unsigned short* A1   = (unsigned short*)(ws);                  // 262,144 B
    unsigned short* A2   = (unsigned short*)(ws + 262144);         // 10,616,832 B
    unsigned short* h1   = (unsigned short*)(ws + 10878976);       // 51,380,224 B
    float*          c2   = (float*)(ws + 62259200);                // 18,874,368 B
    float*          caps = (float*)(ws + 81133568);                // 18,874,368 B
    float*          V    = (float*)(ws + 100007936);               // 20,480 B
    float*          Wv   = (float*)(ws + 100028416);               // 327,680 B
    float*          G    = (float*)(ws + 100356096);               // 327,680 B

    hipLaunchKernelGGL(cvt_w1, dim3(256), dim3(256), 0, stream, w1, A1);
    hipLaunchKernelGGL(cvt_w2, dim3(20736), dim3(256), 0, stream, w2, A2);
    hipLaunchKernelGGL(conv1_gemm, dim3(784, 2), dim3(256), 0, stream, A1, x, b1, h1);
    hipLaunchKernelGGL(conv2_gemm, dim3(144, 2), dim3(256), 0, stream, A2, h1, b2, c2);
    hipLaunchKernelGGL(squash_caps, dim3(2304), dim3(256), 0, stream, c2, caps);
    hipMemsetAsync(V, 0, 5120 * sizeof(float), stream);
    for (int it = 0; it < 3; ++it) {
        hipLaunchKernelGGL(wv_kernel, dim3(32, 32), dim3(80), 0, stream, rw, V, Wv);
        hipLaunchKernelGGL(route_accum, dim3(32, 32), dim3(64), 0, stream, caps, Wv, G);
        hipLaunchKernelGGL(sv_kernel, dim3(32), dim3(160), 0, stream, G, rw, V,
                           (float*)d_out, it == 2 ? 1 : 0);
    }
}

// Round 2
// 673.383 us; speedup vs baseline: 1.9757x; 1.9757x over previous
//
#include <hip/hip_runtime.h>
#include <hip/hip_bf16.h>
#include <stdint.h>

typedef __attribute__((ext_vector_type(8))) short short8;
typedef __attribute__((ext_vector_type(4))) float f32x4;

__device__ inline unsigned short f2bf(float f) {
    union { float f; uint32_t u; } v; v.f = f;
    uint32_t u = v.u;
    uint32_t r = (u + 0x7FFFu + ((u >> 16) & 1u)) >> 16;
    return (unsigned short)r;
}

// ---------------- weight converts ----------------
__global__ void cvt_w1(const float* __restrict__ w, unsigned short* __restrict__ A1) {
    int idx = blockIdx.x * 256 + threadIdx.x;   // 65536 total
    int row = idx >> 8, k = idx & 255;
    float v = (k < 243) ? w[row * 243 + k] : 0.f;
    A1[idx] = f2bf(v);
}

// K-reordered conv2 weights. K order:
//   section 1: k in [0,18432): pair pp=k>>1; ic=pp/36; rem=pp%36; ky=rem>>2; kx=2*(rem&3)+(k&1)
//              (so each even/odd k-pair shares (ic,ky) with adjacent kx -> one u32 im2col load)
//   section 2: k in [18432,20736): j2=k-18432; ic=j2/9; ky=j2%9; kx=8
__global__ void cvt_w2(const float* __restrict__ w, unsigned short* __restrict__ A2) {
    int idx = blockIdx.x * 256 + threadIdx.x;   // 5308416 total
    int oc = idx / 20736, k = idx % 20736;
    int ic, ky, kx;
    if (k < 18432) {
        int pp = k >> 1, odd = k & 1;
        ic = pp / 36;
        int rem = pp % 36;
        ky = rem >> 2;
        kx = ((rem & 3) << 1) | odd;
    } else {
        int j2 = k - 18432;
        ic = j2 / 9; ky = j2 % 9; kx = 8;
    }
    A2[idx] = f2bf(w[((oc * 256 + ic) * 9 + ky) * 9 + kx]);
}

// ---------------- conv1 as implicit GEMM ----------------
// C[oc, n] = sum_k A1[oc,k] * im2col(x)[k,n];  K=243 (padded 256), N=32*56*56=100352
__global__ __launch_bounds__(256) void conv1_gemm(
    const unsigned short* __restrict__ A,   // [256][256] bf16
    const float* __restrict__ x,            // [32][3][64][64]
    const float* __restrict__ bias,         // [256]
    unsigned short* __restrict__ h1)        // [32][256][56][56] bf16
{
    __shared__ unsigned short As[128 * 40];
    __shared__ unsigned short Bs[128 * 40];
    const int tid = threadIdx.x;
    const int m0 = blockIdx.y * 128;
    const int n0 = blockIdx.x * 128;
    const int lane = tid & 63;
    const int wave = tid >> 6;
    const int wy = wave & 1, wx = wave >> 1;
    const int l16 = lane & 15, q = lane >> 4;

    const int kp = tid & 15;
    const int gn = tid >> 4;
    int baseN[8];
#pragma unroll
    for (int j = 0; j < 8; ++j) {
        int n = n0 + gn * 8 + j;
        int b = n / 3136, p = n % 3136;
        int oy = p / 56, ox = p % 56;
        baseN[j] = b * 12288 + oy * 64 + ox;
    }

    f32x4 acc[4][4];
#pragma unroll
    for (int im = 0; im < 4; ++im)
#pragma unroll
        for (int in = 0; in < 4; ++in)
            acc[im][in] = (f32x4){0.f, 0.f, 0.f, 0.f};

    for (int k0 = 0; k0 < 256; k0 += 32) {
        __syncthreads();
#pragma unroll
        for (int s = 0; s < 2; ++s) {
            int slot = tid + s * 256;
            int row = slot >> 2, seg = slot & 3;
            uint4 v = *(const uint4*)(A + (m0 + row) * 256 + k0 + seg * 8);
            *(uint4*)(&As[row * 40 + seg * 8]) = v;
        }
        int ka = k0 + 2 * kp, kb = ka + 1;
        int offa = 0, offb = 0;
        bool va = ka < 243, vb = kb < 243;
        if (va) { int c = ka / 81, t = ka % 81, ky = t / 9, kx = t % 9; offa = c * 4096 + ky * 64 + kx; }
        if (vb) { int c = kb / 81, t = kb % 81, ky = t / 9, kx = t % 9; offb = c * 4096 + ky * 64 + kx; }
#pragma unroll
        for (int j = 0; j < 8; ++j) {
            unsigned int ba = va ? (unsigned int)f2bf(x[baseN[j] + offa]) : 0u;
            unsigned int bb = vb ? (unsigned int)f2bf(x[baseN[j] + offb]) : 0u;
            *(unsigned int*)(&Bs[(gn * 8 + j) * 40 + 2 * kp]) = ba | (bb << 16);
        }
        __syncthreads();

        short8 af[4], bf[4];
#pragma unroll
        for (int im = 0; im < 4; ++im)
            af[im] = *(const short8*)(&As[(wy * 64 + im * 16 + l16) * 40 + q * 8]);
#pragma unroll
        for (int in = 0; in < 4; ++in)
            bf[in] = *(const short8*)(&Bs[(wx * 64 + in * 16 + l16) * 40 + q * 8]);
#pragma unroll
        for (int im = 0; im < 4; ++im)
#pragma unroll
            for (int in = 0; in < 4; ++in)
                acc[im][in] = __builtin_amdgcn_mfma_f32_16x16x32_bf16(af[im], bf[in], acc[im][in], 0, 0, 0);
    }

#pragma unroll
    for (int in = 0; in < 4; ++in) {
        int n = n0 + wx * 64 + in * 16 + l16;
        int b = n / 3136, p = n % 3136;
        int oy = p / 56, ox = p % 56;
#pragma unroll
        for (int im = 0; im < 4; ++im) {
#pragma unroll
            for (int r = 0; r < 4; ++r) {
                int oc = m0 + wy * 64 + im * 16 + q * 4 + r;
                float v = acc[im][in][r] + bias[oc];
                v = v > 0.f ? v : 0.f;
                h1[((b * 256 + oc) * 56 + oy) * 56 + ox] = f2bf(v);
            }
        }
    }
}

// ---------------- conv2 as implicit GEMM, split-K x4 ----------------
// C[oc, n] = sum_k A2[oc,k'] * im2col(h1)[k',n]; K=20736 (reordered), N=18432, stride 2
// Partials atomically added into c2 (zero-initialized; bias applied in squash).
__global__ __launch_bounds__(256) void conv2_gemm(
    const unsigned short* __restrict__ A,   // [256][20736] bf16, K-reordered
    const unsigned short* __restrict__ h1,  // [32][256][56][56] bf16
    float* __restrict__ c2)                 // [32][256][576] fp32 (pre-zeroed)
{
    __shared__ unsigned short As[128 * 40];
    __shared__ unsigned short Bs[128 * 40];
    const int tid = threadIdx.x;
    const int m0 = blockIdx.y * 128;
    const int n0 = blockIdx.x * 128;
    const int lane = tid & 63;
    const int wave = tid >> 6;
    const int wy = wave & 1, wx = wave >> 1;
    const int l16 = lane & 15, q = lane >> 4;

    const int kp = tid & 15;   // k-pair within BK=32
    const int g  = tid >> 4;   // n-group of 8 (aligned to 8 -> single h1 row)
    // n-group geometry: n = n0 + g*8 (+j). 576 = 24*24 per image; groups of 8 never
    // cross an output row since 24 % 8 == 0 and n0 % 8 == 0.
    const int n = n0 + g * 8;
    const int b = n / 576, p = n % 576;
    const int oy = p / 24, ox0 = p % 24;
    // base u16 index into h1 for (b, ic=0, iy=2*oy, x=2*ox0)
    const int cbase = b * 802816 + (2 * oy) * 56 + 2 * ox0;
    const unsigned int* __restrict__ h1u = (const unsigned int*)h1;

    f32x4 acc[4][4];
#pragma unroll
    for (int im = 0; im < 4; ++im)
#pragma unroll
        for (int in = 0; in < 4; ++in)
            acc[im][in] = (f32x4){0.f, 0.f, 0.f, 0.f};

    const int kstart = blockIdx.z * 5184;     // 20736 / 4
    const int kend = kstart + 5184;
    for (int k0 = kstart; k0 < kend; k0 += 32) {
        __syncthreads();
        // stage A (128 x 32), coalesced 16B loads
#pragma unroll
        for (int s = 0; s < 2; ++s) {
            int slot = tid + s * 256;
            int row = slot >> 2, seg = slot & 3;
            uint4 v = *(const uint4*)(A + (m0 + row) * 20736 + k0 + seg * 8);
            *(uint4*)(&As[row * 40 + seg * 8]) = v;
        }
        // stage B: k-pair (2kp,2kp+1) -> one u32 per output col (section 1)
        int k = k0 + 2 * kp;
        if (k < 18432) {
            int pp = k >> 1;
            int ic = pp / 36;
            int rem = pp % 36;
            int ky = rem >> 2, kx = (rem & 3) << 1;
            const unsigned int* src = h1u + ((cbase + ic * 3136 + ky * 56 + kx) >> 1);
#pragma unroll
            for (int j = 0; j < 8; ++j)
                *(unsigned int*)(&Bs[(g * 8 + j) * 40 + 2 * kp]) = src[j];
        } else {
            // tail: both k of the pair have kx=8, different (ic,ky)
            int j2 = k - 18432;
            int icA = j2 / 9, kyA = j2 % 9;
            int j2b = j2 + 1;
            int icB = j2b / 9, kyB = j2b % 9;
            int baseA = cbase + icA * 3136 + kyA * 56 + 8;
            int baseB = cbase + icB * 3136 + kyB * 56 + 8;
#pragma unroll
            for (int j = 0; j < 8; ++j) {
                unsigned int ba = (unsigned int)h1[baseA + 2 * j];
                unsigned int bb = (unsigned int)h1[baseB + 2 * j];
                *(unsigned int*)(&Bs[(g * 8 + j) * 40 + 2 * kp]) = ba | (bb << 16);
            }
        }
        __syncthreads();

        short8 af[4], bf[4];
#pragma unroll
        for (int im = 0; im < 4; ++im)
            af[im] = *(const short8*)(&As[(wy * 64 + im * 16 + l16) * 40 + q * 8]);
#pragma unroll
        for (int in = 0; in < 4; ++in)
            bf[in] = *(const short8*)(&Bs[(wx * 64 + in * 16 + l16) * 40 + q * 8]);
#pragma unroll
        for (int im = 0; im < 4; ++im)
#pragma unroll
            for (int in = 0; in < 4; ++in)
                acc[im][in] = __builtin_amdgcn_mfma_f32_16x16x32_bf16(af[im], bf[in], acc[im][in], 0, 0, 0);
    }

    // epilogue: accumulate split-K partial into c2
#pragma unroll
    for (int in = 0; in < 4; ++in) {
        int nn = n0 + wx * 64 + in * 16 + l16;
        int bb = nn / 576, pp = nn % 576;
#pragma unroll
        for (int im = 0; im < 4; ++im) {
#pragma unroll
            for (int r = 0; r < 4; ++r) {
                int oc = m0 + wy * 64 + im * 16 + q * 4 + r;
                atomicAdd(&c2[(bb * 256 + oc) * 576 + pp], acc[im][in][r]);
            }
        }
    }
}

// ---------------- squash primary caps (+ conv2 bias) ----------------
__global__ void squash_caps(const float* __restrict__ c2, const float* __restrict__ bias,
                            float* __restrict__ caps) {
    int idx = blockIdx.x * 256 + threadIdx.x;   // 589824 = 32*32*576
    int b = idx / 18432;
    int rp = idx % 18432;
    int r = rp / 576, p = rp % 576;
    float s[8]; float n2 = 0.f;
#pragma unroll
    for (int d = 0; d < 8; ++d) {
        s[d] = c2[(b * 256 + r * 8 + d) * 576 + p] + bias[r * 8 + d];
        n2 += s[d] * s[d];
    }
    float sc = (n2 / (1.f + n2)) / sqrtf(n2 + 1e-8f);
#pragma unroll
    for (int d = 0; d < 8; ++d)
        caps[idx * 8 + d] = sc * s[d];
}

// ---------------- routing ----------------
__global__ void wv_kernel(const float* __restrict__ W, const float* __restrict__ V,
                          float* __restrict__ Wv) {
    int r = blockIdx.x, b = blockIdx.y;
    int c = threadIdx.x / 8, i = threadIdx.x % 8;   // 80 threads
    float s = 0.f;
#pragma unroll
    for (int o = 0; o < 16; ++o)
        s += W[((r * 10 + c) * 8 + i) * 16 + o] * V[(b * 10 + c) * 16 + o];
    Wv[(b * 32 + r) * 80 + c * 8 + i] = s;
}

__global__ __launch_bounds__(64) void route_accum(const float* __restrict__ caps,
                                                  const float* __restrict__ Wv,
                                                  float* __restrict__ G) {
    int r = blockIdx.x, b = blockIdx.y;
    __shared__ float wv[80];
    __shared__ float red[80][64];
    int tid = threadIdx.x;
    for (int v = tid; v < 80; v += 64) wv[v] = Wv[(b * 32 + r) * 80 + v];
    __syncthreads();
    float g[80];
#pragma unroll
    for (int v = 0; v < 80; ++v) g[v] = 0.f;
    const float* cp = caps + (size_t)(b * 32 + r) * 576 * 8;
    for (int j = 0; j < 9; ++j) {
        int p = j * 64 + tid;
        const f32x4* qp = (const f32x4*)(cp + p * 8);
        f32x4 c0 = qp[0], c1 = qp[1];
        float c8[8];
#pragma unroll
        for (int i = 0; i < 4; ++i) { c8[i] = c0[i]; c8[4 + i] = c1[i]; }
        float a[10]; float m = -1e30f;
#pragma unroll
        for (int c = 0; c < 10; ++c) {
            float t = 0.f;
#pragma unroll
            for (int i = 0; i < 8; ++i) t += c8[i] * wv[c * 8 + i];
            a[c] = t; m = fmaxf(m, t);
        }
        float sum = 0.f;
#pragma unroll
        for (int c = 0; c < 10; ++c) { a[c] = __expf(a[c] - m); sum += a[c]; }
        float inv = 1.f / sum;
#pragma unroll
        for (int c = 0; c < 10; ++c) {
            float cc = a[c] * inv;
#pragma unroll
            for (int i = 0; i < 8; ++i) g[c * 8 + i] += cc * c8[i];
        }
    }
#pragma unroll
    for (int v = 0; v < 80; ++v) red[v][tid] = g[v];
    __syncthreads();
    for (int v = tid; v < 80; v += 64) {
        float s = 0.f;
        for (int t = 0; t < 64; ++t) s += red[v][t];
        G[(b * 32 + r) * 80 + v] = s;
    }
}

__global__ __launch_bounds__(160) void sv_kernel(const float* __restrict__ G,
                                                 const float* __restrict__ W,
                                                 float* __restrict__ V,
                                                 float* __restrict__ out, int last) {
    int b = blockIdx.x;
    int c = threadIdx.x / 16, o = threadIdx.x % 16;
    __shared__ float sL[10][16];
    float s = 0.f;
    for (int r = 0; r < 32; ++r) {
        const float* g = G + ((b * 32 + r) * 10 + c) * 8;
        const float* w = W + ((r * 10 + c) * 8) * 16 + o;
#pragma unroll
        for (int i = 0; i < 8; ++i) s += g[i] * w[i * 16];
    }
    sL[c][o] = s;
    __syncthreads();
    float n2 = 0.f;
#pragma unroll
    for (int oo = 0; oo < 16; ++oo) { float t = sL[c][oo]; n2 += t * t; }
    float sc = (n2 / (1.f + n2)) / sqrtf(n2 + 1e-8f);
    float v = sc * s;
    V[(b * 10 + c) * 16 + o] += v;
    if (last) out[(b * 10 + c) * 16 + o] = v;
}

// ---------------- launch ----------------
extern "C" void kernel_launch(void* const* d_in, const int* in_sizes, int n_in,
                              void* d_out, int out_size, void* d_ws, size_t ws_size,
                              hipStream_t stream) {
    const float* x  = (const float*)d_in[0];
    const float* w1 = (const float*)d_in[1];
    const float* b1 = (const float*)d_in[2];
    const float* w2 = (const float*)d_in[3];
    const float* b2 = (const float*)d_in[4];
    const float* rw = (const float*)d_in[5];

    char* ws = (char*)d_ws;
    unsigned short* A1   = (unsigned short*)(ws);                  // 262,144 B
    unsigned short* A2   = (unsigned short*)(ws + 262144);         // 10,616,832 B
    unsigned short* h1   = (unsigned short*)(ws + 10878976);       // 51,380,224 B
    float*          c2   = (float*)(ws + 62259200);                // 18,874,368 B
    float*          caps = (float*)(ws + 81133568);                // 18,874,368 B
    float*          V    = (float*)(ws + 100007936);               // 20,480 B
    float*          Wv   = (float*)(ws + 100028416);               // 327,680 B
    float*          G    = (float*)(ws + 100356096);               // 327,680 B

    hipLaunchKernelGGL(cvt_w1, dim3(256), dim3(256), 0, stream, w1, A1);
    hipLaunchKernelGGL(cvt_w2, dim3(20736), dim3(256), 0, stream, w2, A2);
    hipMemsetAsync(c2, 0, 18874368, stream);
    hipLaunchKernelGGL(conv1_gemm, dim3(784, 2), dim3(256), 0, stream, A1, x, b1, h1);
    hipLaunchKernelGGL(conv2_gemm, dim3(144, 2, 4), dim3(256), 0, stream, A2, h1, c2);
    hipLaunchKernelGGL(squash_caps, dim3(2304), dim3(256), 0, stream, c2, b2, caps);
    hipMemsetAsync(V, 0, 5120 * sizeof(float), stream);
    for (int it = 0; it < 3; ++it) {
        hipLaunchKernelGGL(wv_kernel, dim3(32, 32), dim3(80), 0, stream, rw, V, Wv);
        hipLaunchKernelGGL(route_accum, dim3(32, 32), dim3(64), 0, stream, caps, Wv, G);
        hipLaunchKernelGGL(sv_kernel, dim3(32), dim3(160), 0, stream, G, rw, V,
                           (float*)d_out, it == 2 ? 1 : 0);
    }
}

// Round 3
// 614.206 us; speedup vs baseline: 2.1661x; 1.0963x over previous
//
#include <hip/hip_runtime.h>
#include <hip/hip_bf16.h>
#include <stdint.h>

typedef __attribute__((ext_vector_type(8))) short short8;
typedef __attribute__((ext_vector_type(4))) float f32x4;
typedef unsigned int u32x4a __attribute__((vector_size(16)));             // 16B aligned
typedef unsigned int u32x4u __attribute__((vector_size(16), aligned(4))); // 4B aligned

__device__ inline unsigned short f2bf(float f) {
    union { float f; uint32_t u; } v; v.f = f;
    uint32_t u = v.u;
    uint32_t r = (u + 0x7FFFu + ((u >> 16) & 1u)) >> 16;
    return (unsigned short)r;
}

// ---------------- weight converts ----------------
__global__ void cvt_w1(const float* __restrict__ w, unsigned short* __restrict__ A1) {
    int idx = blockIdx.x * 256 + threadIdx.x;   // 65536 total
    int row = idx >> 8, k = idx & 255;
    float v = (k < 243) ? w[row * 243 + k] : 0.f;
    A1[idx] = f2bf(v);
}

// K-reordered conv2 weights:
//   k < 18432:  k = ic*72 + ky*8 + kx   (kx 0..7 -> octet-contiguous)
//   k >= 18432: j2 = k-18432; ic=j2/9; ky=j2%9; kx=8
__global__ void cvt_w2(const float* __restrict__ w, unsigned short* __restrict__ A2) {
    int idx = blockIdx.x * 256 + threadIdx.x;   // 5308416 total
    int oc = idx / 20736, k = idx % 20736;
    int ic, ky, kx;
    if (k < 18432) {
        ic = k / 72;
        int rem = k % 72;
        ky = rem >> 3;
        kx = rem & 7;
    } else {
        int j2 = k - 18432;
        ic = j2 / 9; ky = j2 % 9; kx = 8;
    }
    A2[idx] = f2bf(w[((oc * 256 + ic) * 9 + ky) * 9 + kx]);
}

// ---------------- conv1 as implicit GEMM ----------------
__global__ __launch_bounds__(256) void conv1_gemm(
    const unsigned short* __restrict__ A,   // [256][256] bf16
    const float* __restrict__ x,            // [32][3][64][64]
    const float* __restrict__ bias,         // [256]
    unsigned short* __restrict__ h1)        // [32][256][56][56] bf16
{
    __shared__ unsigned short As[128 * 40];
    __shared__ unsigned short Bs[128 * 40];
    const int tid = threadIdx.x;
    const int m0 = blockIdx.y * 128;
    const int n0 = blockIdx.x * 128;
    const int lane = tid & 63;
    const int wave = tid >> 6;
    const int wy = wave & 1, wx = wave >> 1;
    const int l16 = lane & 15, q = lane >> 4;

    const int kp = tid & 15;
    const int gn = tid >> 4;
    int baseN[8];
#pragma unroll
    for (int j = 0; j < 8; ++j) {
        int n = n0 + gn * 8 + j;
        int b = n / 3136, p = n % 3136;
        int oy = p / 56, ox = p % 56;
        baseN[j] = b * 12288 + oy * 64 + ox;
    }

    f32x4 acc[4][4];
#pragma unroll
    for (int im = 0; im < 4; ++im)
#pragma unroll
        for (int in = 0; in < 4; ++in)
            acc[im][in] = (f32x4){0.f, 0.f, 0.f, 0.f};

    for (int k0 = 0; k0 < 256; k0 += 32) {
        __syncthreads();
#pragma unroll
        for (int s = 0; s < 2; ++s) {
            int slot = tid + s * 256;
            int row = slot >> 2, seg = slot & 3;
            u32x4a v = *(const u32x4a*)(A + (m0 + row) * 256 + k0 + seg * 8);
            *(u32x4a*)(&As[row * 40 + seg * 8]) = v;
        }
        int ka = k0 + 2 * kp, kb = ka + 1;
        int offa = 0, offb = 0;
        bool va = ka < 243, vb = kb < 243;
        if (va) { int c = ka / 81, t = ka % 81, ky = t / 9, kx = t % 9; offa = c * 4096 + ky * 64 + kx; }
        if (vb) { int c = kb / 81, t = kb % 81, ky = t / 9, kx = t % 9; offb = c * 4096 + ky * 64 + kx; }
#pragma unroll
        for (int j = 0; j < 8; ++j) {
            unsigned int ba = va ? (unsigned int)f2bf(x[baseN[j] + offa]) : 0u;
            unsigned int bb = vb ? (unsigned int)f2bf(x[baseN[j] + offb]) : 0u;
            *(unsigned int*)(&Bs[(gn * 8 + j) * 40 + 2 * kp]) = ba | (bb << 16);
        }
        __syncthreads();

        short8 af[4], bf[4];
#pragma unroll
        for (int im = 0; im < 4; ++im)
            af[im] = *(const short8*)(&As[(wy * 64 + im * 16 + l16) * 40 + q * 8]);
#pragma unroll
        for (int in = 0; in < 4; ++in)
            bf[in] = *(const short8*)(&Bs[(wx * 64 + in * 16 + l16) * 40 + q * 8]);
#pragma unroll
        for (int im = 0; im < 4; ++im)
#pragma unroll
            for (int in = 0; in < 4; ++in)
                acc[im][in] = __builtin_amdgcn_mfma_f32_16x16x32_bf16(af[im], bf[in], acc[im][in], 0, 0, 0);
    }

#pragma unroll
    for (int in = 0; in < 4; ++in) {
        int n = n0 + wx * 64 + in * 16 + l16;
        int b = n / 3136, p = n % 3136;
        int oy = p / 56, ox = p % 56;
#pragma unroll
        for (int im = 0; im < 4; ++im) {
#pragma unroll
            for (int r = 0; r < 4; ++r) {
                int oc = m0 + wy * 64 + im * 16 + q * 4 + r;
                float v = acc[im][in][r] + bias[oc];
                v = v > 0.f ? v : 0.f;
                h1[((b * 256 + oc) * 56 + oy) * 56 + ox] = f2bf(v);
            }
        }
    }
}

// ---------------- conv2 as implicit GEMM, split-K x4 (strided), BK=64 ----------------
// C[oc, n] = sum_k A2[oc,k'] * im2col(h1)[k',n]; K=20736 (octet-reordered), N=18432
// Each z walks k0 = z*64 + 256*i (i=0..80) so kx=8 tail iters spread evenly.
#define C2ROW 72   // LDS row pitch in ushorts (144 B: 16B-aligned, (row+seg)%8 bank groups)
__global__ __launch_bounds__(256) void conv2_gemm(
    const unsigned short* __restrict__ A,   // [256][20736] bf16, K-reordered
    const unsigned short* __restrict__ h1,  // [32][256][56][56] bf16
    float* __restrict__ c2)                 // [32][256][576] fp32 (pre-zeroed)
{
    __shared__ unsigned short As[128 * C2ROW];
    __shared__ unsigned short Bs[128 * C2ROW];
    const int tid = threadIdx.x;
    const int m0 = blockIdx.y * 128;
    const int n0 = blockIdx.x * 128;
    const int z = blockIdx.z;
    const int lane = tid & 63;
    const int wave = tid >> 6;
    const int wy = wave & 1, wx = wave >> 1;
    const int l16 = lane & 15, q = lane >> 4;

    // A staging: slot = tid + 256*s, row = slot>>3, seg = slot&7
    const int arow = tid >> 3;
    const int aseg = tid & 7;
    const size_t abase = (size_t)(m0 + arow) * 20736 + aseg * 8;

    // B octet staging: thread covers oct = tid>>5 at 4 n's: n = (tid&31) + 32*i
    const int oct = tid >> 5;
    int bsrc[4];   // h1 base idx (b,iy0,x0) per n
    int bdst[4];   // LDS ushort offset
#pragma unroll
    for (int i = 0; i < 4; ++i) {
        int n = (tid & 31) + 32 * i;
        int ng = n0 + n;
        int b = ng / 576, p = ng % 576;
        int oy = p / 24, ox = p % 24;
        bsrc[i] = b * 802816 + (2 * oy) * 56 + 2 * ox;
        bdst[i] = n * C2ROW + oct * 8;
    }
    // tail staging geometry: thread covers n = tid&127, k-half = tid>>7
    const int tn = tid & 127;
    const int thalf = tid >> 7;
    int tbase;
    {
        int ng = n0 + tn;
        int b = ng / 576, p = ng % 576;
        int oy = p / 24, ox = p % 24;
        tbase = b * 802816 + (2 * oy) * 56 + 2 * ox + 8;   // kx = 8
    }

    f32x4 acc[4][4];
#pragma unroll
    for (int im = 0; im < 4; ++im)
#pragma unroll
        for (int in = 0; in < 4; ++in)
            acc[im][in] = (f32x4){0.f, 0.f, 0.f, 0.f};

    for (int it = 0; it < 81; ++it) {
        const int k0 = z * 64 + it * 256;
        __syncthreads();
        // ---- stage A: 128 x 64, 4x dwordx4 per thread, ds_write_b128 ----
#pragma unroll
        for (int s = 0; s < 4; ++s) {
            u32x4a v = *(const u32x4a*)(A + abase + (size_t)s * 32 * 20736 + k0);
            *(u32x4a*)(&As[(arow + 32 * s) * C2ROW + aseg * 8]) = v;
        }
        // ---- stage B ----
        if (k0 < 18432) {
            int octk = (k0 >> 3) + oct;
            int ic = octk / 9;
            int ky = octk - ic * 9;
            int off = ic * 3136 + ky * 56;
#pragma unroll
            for (int i = 0; i < 4; ++i) {
                u32x4u v = *(const u32x4u*)(h1 + bsrc[i] + off);
                *(u32x4a*)(&Bs[bdst[i]]) = (u32x4a)v;
            }
        } else {
#pragma unroll
            for (int j = 0; j < 16; ++j) {
                int kk = thalf * 32 + 2 * j;
                int j2 = k0 + kk - 18432;
                int icA = j2 / 9, kyA = j2 - icA * 9;
                int j2b = j2 + 1;
                int icB = j2b / 9, kyB = j2b - icB * 9;
                unsigned int ba = (unsigned int)h1[tbase + icA * 3136 + kyA * 56];
                unsigned int bb = (unsigned int)h1[tbase + icB * 3136 + kyB * 56];
                *(unsigned int*)(&Bs[tn * C2ROW + kk]) = ba | (bb << 16);
            }
        }
        __syncthreads();

        // ---- compute: 2 chunks of K=32 ----
#pragma unroll
        for (int c = 0; c < 2; ++c) {
            short8 af[4], bf[4];
#pragma unroll
            for (int im = 0; im < 4; ++im)
                af[im] = *(const short8*)(&As[(wy * 64 + im * 16 + l16) * C2ROW + c * 32 + q * 8]);
#pragma unroll
            for (int in = 0; in < 4; ++in)
                bf[in] = *(const short8*)(&Bs[(wx * 64 + in * 16 + l16) * C2ROW + c * 32 + q * 8]);
#pragma unroll
            for (int im = 0; im < 4; ++im)
#pragma unroll
                for (int in = 0; in < 4; ++in)
                    acc[im][in] = __builtin_amdgcn_mfma_f32_16x16x32_bf16(af[im], bf[in], acc[im][in], 0, 0, 0);
        }
    }

    // epilogue: accumulate split-K partial into c2
#pragma unroll
    for (int in = 0; in < 4; ++in) {
        int nn = n0 + wx * 64 + in * 16 + l16;
        int bb = nn / 576, pp = nn % 576;
#pragma unroll
        for (int im = 0; im < 4; ++im) {
#pragma unroll
            for (int r = 0; r < 4; ++r) {
                int oc = m0 + wy * 64 + im * 16 + q * 4 + r;
                atomicAdd(&c2[(bb * 256 + oc) * 576 + pp], acc[im][in][r]);
            }
        }
    }
}

// ---------------- squash primary caps (+ conv2 bias) ----------------
__global__ void squash_caps(const float* __restrict__ c2, const float* __restrict__ bias,
                            float* __restrict__ caps) {
    int idx = blockIdx.x * 256 + threadIdx.x;   // 589824 = 32*32*576
    int b = idx / 18432;
    int rp = idx % 18432;
    int r = rp / 576, p = rp % 576;
    float s[8]; float n2 = 0.f;
#pragma unroll
    for (int d = 0; d < 8; ++d) {
        s[d] = c2[(b * 256 + r * 8 + d) * 576 + p] + bias[r * 8 + d];
        n2 += s[d] * s[d];
    }
    float sc = (n2 / (1.f + n2)) / sqrtf(n2 + 1e-8f);
#pragma unroll
    for (int d = 0; d < 8; ++d)
        caps[idx * 8 + d] = sc * s[d];
}

// ---------------- routing ----------------
__global__ void wv_kernel(const float* __restrict__ W, const float* __restrict__ V,
                          float* __restrict__ Wv) {
    int r = blockIdx.x, b = blockIdx.y;
    int c = threadIdx.x / 8, i = threadIdx.x % 8;   // 80 threads
    float s = 0.f;
#pragma unroll
    for (int o = 0; o < 16; ++o)
        s += W[((r * 10 + c) * 8 + i) * 16 + o] * V[(b * 10 + c) * 16 + o];
    Wv[(b * 32 + r) * 80 + c * 8 + i] = s;
}

__global__ __launch_bounds__(64) void route_accum(const float* __restrict__ caps,
                                                  const float* __restrict__ Wv,
                                                  float* __restrict__ G) {
    int r = blockIdx.x, b = blockIdx.y;
    __shared__ float wv[80];
    __shared__ float red[80][64];
    int tid = threadIdx.x;
    for (int v = tid; v < 80; v += 64) wv[v] = Wv[(b * 32 + r) * 80 + v];
    __syncthreads();
    float g[80];
#pragma unroll
    for (int v = 0; v < 80; ++v) g[v] = 0.f;
    const float* cp = caps + (size_t)(b * 32 + r) * 576 * 8;
    for (int j = 0; j < 9; ++j) {
        int p = j * 64 + tid;
        const f32x4* qp = (const f32x4*)(cp + p * 8);
        f32x4 c0 = qp[0], c1 = qp[1];
        float c8[8];
#pragma unroll
        for (int i = 0; i < 4; ++i) { c8[i] = c0[i]; c8[4 + i] = c1[i]; }
        float a[10]; float m = -1e30f;
#pragma unroll
        for (int c = 0; c < 10; ++c) {
            float t = 0.f;
#pragma unroll
            for (int i = 0; i < 8; ++i) t += c8[i] * wv[c * 8 + i];
            a[c] = t; m = fmaxf(m, t);
        }
        float sum = 0.f;
#pragma unroll
        for (int c = 0; c < 10; ++c) { a[c] = __expf(a[c] - m); sum += a[c]; }
        float inv = 1.f / sum;
#pragma unroll
        for (int c = 0; c < 10; ++c) {
            float cc = a[c] * inv;
#pragma unroll
            for (int i = 0; i < 8; ++i) g[c * 8 + i] += cc * c8[i];
        }
    }
#pragma unroll
    for (int v = 0; v < 80; ++v) red[v][tid] = g[v];
    __syncthreads();
    for (int v = tid; v < 80; v += 64) {
        float s = 0.f;
        for (int t = 0; t < 64; ++t) s += red[v][t];
        G[(b * 32 + r) * 80 + v] = s;
    }
}

__global__ __launch_bounds__(160) void sv_kernel(const float* __restrict__ G,
                                                 const float* __restrict__ W,
                                                 float* __restrict__ V,
                                                 float* __restrict__ out, int last) {
    int b = blockIdx.x;
    int c = threadIdx.x / 16, o = threadIdx.x % 16;
    __shared__ float sL[10][16];
    float s = 0.f;
    for (int r = 0; r < 32; ++r) {
        const float* g = G + ((b * 32 + r) * 10 + c) * 8;
        const float* w = W + ((r * 10 + c) * 8) * 16 + o;
#pragma unroll
        for (int i = 0; i < 8; ++i) s += g[i] * w[i * 16];
    }
    sL[c][o] = s;
    __syncthreads();
    float n2 = 0.f;
#pragma unroll
    for (int oo = 0; oo < 16; ++oo) { float t = sL[c][oo]; n2 += t * t; }
    float sc = (n2 / (1.f + n2)) / sqrtf(n2 + 1e-8f);
    float v = sc * s;
    V[(b * 10 + c) * 16 + o] += v;
    if (last) out[(b * 10 + c) * 16 + o] = v;
}

// ---------------- launch ----------------
extern "C" void kernel_launch(void* const* d_in, const int* in_sizes, int n_in,
                              void* d_out, int out_size, void* d_ws, size_t ws_size,
                              hipStream_t stream) {
    const float* x  = (const float*)d_in[0];
    const float* w1 = (const float*)d_in[1];
    const float* b1 = (const float*)d_in[2];
    const float* w2 = (const float*)d_in[3];
    const float* b2 = (const float*)d_in[4];
    const float* rw = (const float*)d_in[5];

    char* ws = (char*)d_ws;
    unsigned short* A1   = (unsigned short*)(ws);                  // 262,144 B
    unsigned short* A2   = (unsigned short*)(ws + 262144);         // 10,616,832 B
    unsigned short* h1   = (unsigned short*)(ws + 10878976);       // 51,380,224 B
    float*          c2   = (float*)(ws + 62259200);                // 18,874,368 B
    float*          caps = (float*)(ws + 81133568);                // 18,874,368 B
    float*          V    = (float*)(ws + 100007936);               // 20,480 B
    float*          Wv   = (float*)(ws + 100028416);               // 327,680 B
    float*          G    = (float*)(ws + 100356096);               // 327,680 B

    hipLaunchKernelGGL(cvt_w1, dim3(256), dim3(256), 0, stream, w1, A1);
    hipLaunchKernelGGL(cvt_w2, dim3(20736), dim3(256), 0, stream, w2, A2);
    hipMemsetAsync(c2, 0, 18874368, stream);
    hipLaunchKernelGGL(conv1_gemm, dim3(784, 2), dim3(256), 0, stream, A1, x, b1, h1);
    hipLaunchKernelGGL(conv2_gemm, dim3(144, 2, 4), dim3(256), 0, stream, A2, h1, c2);
    hipLaunchKernelGGL(squash_caps, dim3(2304), dim3(256), 0, stream, c2, b2, caps);
    hipMemsetAsync(V, 0, 5120 * sizeof(float), stream);
    for (int it = 0; it < 3; ++it) {
        hipLaunchKernelGGL(wv_kernel, dim3(32, 32), dim3(80), 0, stream, rw, V, Wv);
        hipLaunchKernelGGL(route_accum, dim3(32, 32), dim3(64), 0, stream, caps, Wv, G);
        hipLaunchKernelGGL(sv_kernel, dim3(32), dim3(160), 0, stream, G, rw, V,
                           (float*)d_out, it == 2 ? 1 : 0);
    }
}

// Round 4
// 470.629 us; speedup vs baseline: 2.8269x; 1.3051x over previous
//
#include <hip/hip_runtime.h>
#include <hip/hip_bf16.h>
#include <stdint.h>

typedef __attribute__((ext_vector_type(8))) short short8;
typedef __attribute__((ext_vector_type(4))) float f32x4;
typedef unsigned int u32x4a __attribute__((vector_size(16)));             // 16B aligned
typedef unsigned int u32x4u __attribute__((vector_size(16), aligned(4))); // 4B aligned

__device__ inline unsigned short f2bf(float f) {
    union { float f; uint32_t u; } v; v.f = f;
    uint32_t u = v.u;
    uint32_t r = (u + 0x7FFFu + ((u >> 16) & 1u)) >> 16;
    return (unsigned short)r;
}

// async global->LDS, 16B per lane
__device__ inline void gl_lds16(const unsigned short* g, unsigned short* l) {
    __builtin_amdgcn_global_load_lds(
        (const uint32_t __attribute__((address_space(1)))*)(const void*)g,
        (uint32_t __attribute__((address_space(3)))*)(void*)l, 16, 0, 0);
}

// ---------------- weight converts ----------------
__global__ void cvt_w1(const float* __restrict__ w, unsigned short* __restrict__ A1) {
    int idx = blockIdx.x * 256 + threadIdx.x;   // 65536 total
    int row = idx >> 8, k = idx & 255;
    float v = (k < 243) ? w[row * 243 + k] : 0.f;
    A1[idx] = f2bf(v);
}

// conv2 weights pre-shuffled into per-(m-tile, K-chunk) 16KB tiles, XOR-swizzled:
// A2t[tm][chunk][off16][j]  (off16 in [0,1024), j in [0,8))
//   row = off16>>3; sw = off16&7; koct = sw ^ (row&7); kk = chunk*64 + koct*8 + j
// reordered-k mapping: kk<18432: ic=kk/72, ky=(kk%72)>>3, kx=kk&7;  else kx=8 tail.
__global__ void cvt_w2(const float* __restrict__ w, unsigned short* __restrict__ A2t) {
    int idx = blockIdx.x * 256 + threadIdx.x;   // 5308416 total
    int j = idx & 7;
    int off16 = (idx >> 3) & 1023;
    int tile = idx >> 13;                 // 0..647
    int tm = tile / 324, chunk = tile - tm * 324;
    int row = off16 >> 3, sw = off16 & 7;
    int koct = sw ^ (row & 7);
    int kk = chunk * 64 + koct * 8 + j;
    int oc = tm * 128 + row;
    int ic, ky, kx;
    if (kk < 18432) { ic = kk / 72; int rem = kk - ic * 72; ky = rem >> 3; kx = rem & 7; }
    else { int j2 = kk - 18432; ic = j2 / 9; ky = j2 - ic * 9; kx = 8; }
    A2t[idx] = f2bf(w[((oc * 256 + ic) * 9 + ky) * 9 + kx]);
}

// ---------------- conv1 as implicit GEMM ----------------
__global__ __launch_bounds__(256) void conv1_gemm(
    const unsigned short* __restrict__ A,   // [256][256] bf16
    const float* __restrict__ x,            // [32][3][64][64]
    const float* __restrict__ bias,         // [256]
    unsigned short* __restrict__ h1)        // [32][256][56][56] bf16
{
    __shared__ __align__(16) unsigned short As[128 * 40];
    __shared__ __align__(16) unsigned short Bs[128 * 40];
    const int tid = threadIdx.x;
    const int m0 = blockIdx.y * 128;
    const int n0 = blockIdx.x * 128;
    const int lane = tid & 63;
    const int wave = tid >> 6;
    const int wy = wave & 1, wx = wave >> 1;
    const int l16 = lane & 15, q = lane >> 4;

    const int kp = tid & 15;
    const int gn = tid >> 4;
    int baseN[8];
#pragma unroll
    for (int j = 0; j < 8; ++j) {
        int n = n0 + gn * 8 + j;
        int b = n / 3136, p = n % 3136;
        int oy = p / 56, ox = p % 56;
        baseN[j] = b * 12288 + oy * 64 + ox;
    }

    f32x4 acc[4][4];
#pragma unroll
    for (int im = 0; im < 4; ++im)
#pragma unroll
        for (int in = 0; in < 4; ++in)
            acc[im][in] = (f32x4){0.f, 0.f, 0.f, 0.f};

    for (int k0 = 0; k0 < 256; k0 += 32) {
        __syncthreads();
#pragma unroll
        for (int s = 0; s < 2; ++s) {
            int slot = tid + s * 256;
            int row = slot >> 2, seg = slot & 3;
            u32x4a v = *(const u32x4a*)(A + (m0 + row) * 256 + k0 + seg * 8);
            *(u32x4a*)(&As[row * 40 + seg * 8]) = v;
        }
        int ka = k0 + 2 * kp, kb = ka + 1;
        int offa = 0, offb = 0;
        bool va = ka < 243, vb = kb < 243;
        if (va) { int c = ka / 81, t = ka % 81, ky = t / 9, kx = t % 9; offa = c * 4096 + ky * 64 + kx; }
        if (vb) { int c = kb / 81, t = kb % 81, ky = t / 9, kx = t % 9; offb = c * 4096 + ky * 64 + kx; }
#pragma unroll
        for (int j = 0; j < 8; ++j) {
            unsigned int ba = va ? (unsigned int)f2bf(x[baseN[j] + offa]) : 0u;
            unsigned int bb = vb ? (unsigned int)f2bf(x[baseN[j] + offb]) : 0u;
            *(unsigned int*)(&Bs[(gn * 8 + j) * 40 + 2 * kp]) = ba | (bb << 16);
        }
        __syncthreads();

        short8 af[4], bf[4];
#pragma unroll
        for (int im = 0; im < 4; ++im)
            af[im] = *(const short8*)(&As[(wy * 64 + im * 16 + l16) * 40 + q * 8]);
#pragma unroll
        for (int in = 0; in < 4; ++in)
            bf[in] = *(const short8*)(&Bs[(wx * 64 + in * 16 + l16) * 40 + q * 8]);
#pragma unroll
        for (int im = 0; im < 4; ++im)
#pragma unroll
            for (int in = 0; in < 4; ++in)
                acc[im][in] = __builtin_amdgcn_mfma_f32_16x16x32_bf16(af[im], bf[in], acc[im][in], 0, 0, 0);
    }

#pragma unroll
    for (int in = 0; in < 4; ++in) {
        int n = n0 + wx * 64 + in * 16 + l16;
        int b = n / 3136, p = n % 3136;
        int oy = p / 56, ox = p % 56;
#pragma unroll
        for (int im = 0; im < 4; ++im) {
#pragma unroll
            for (int r = 0; r < 4; ++r) {
                int oc = m0 + wy * 64 + im * 16 + q * 4 + r;
                float v = acc[im][in][r] + bias[oc];
                v = v > 0.f ? v : 0.f;
                h1[((b * 256 + oc) * 56 + oy) * 56 + ox] = f2bf(v);
            }
        }
    }
}

// ---------------- conv2: pipelined implicit GEMM, split-K x8, BK=64 ----------------
// A staged via global_load_lds (double-buffered, swizzled tiles); B prefetched to regs.
#define C2ROW 72
__global__ __launch_bounds__(256) void conv2_gemm(
    const unsigned short* __restrict__ A2t,  // [2][324][8192] bf16 swizzled tiles
    const unsigned short* __restrict__ h1,   // [32][256][56][56] bf16
    float* __restrict__ c2)                  // [32][256][576] fp32 (pre-zeroed)
{
    __shared__ __align__(16) unsigned short As[2][8192];   // 2 x 16KB
    __shared__ __align__(16) unsigned short Bs[128 * C2ROW];
    const int tid = threadIdx.x;
    const int n0 = blockIdx.x * 128;
    const int z = blockIdx.z;
    const int lane = tid & 63;
    const int wave = tid >> 6;
    const int wy = wave & 1, wx = wave >> 1;
    const int l16 = lane & 15, q = lane >> 4;

    // B octet staging geometry
    const int oct = tid >> 5;
    int bsrc[4], bdst[4];
#pragma unroll
    for (int i = 0; i < 4; ++i) {
        int n = (tid & 31) + 32 * i;
        int ng = n0 + n;
        int b = ng / 576, p = ng % 576;
        int oy = p / 24, ox = p % 24;
        bsrc[i] = b * 802816 + (2 * oy) * 56 + 2 * ox;
        bdst[i] = n * C2ROW + oct * 8;
    }
    // B tail staging geometry
    const int tn = tid & 127, thalf = tid >> 7;
    int tbase;
    {
        int ng = n0 + tn;
        int b = ng / 576, p = ng % 576;
        int oy = p / 24, ox = p % 24;
        tbase = b * 802816 + (2 * oy) * 56 + 2 * ox + 8;   // kx = 8
    }

    f32x4 acc[4][4];
#pragma unroll
    for (int im = 0; im < 4; ++im)
#pragma unroll
        for (int in = 0; in < 4; ++in)
            acc[im][in] = (f32x4){0.f, 0.f, 0.f, 0.f};

    const size_t tilebase = (size_t)blockIdx.y * 324 * 8192;
    uint32_t bR[16];

    auto issueA = [&](int c, int buf) {
        const unsigned short* at = A2t + tilebase + (size_t)c * 8192;
        int s0 = wave * 4;
#pragma unroll
        for (int i = 0; i < 4; ++i) {
            int sl = (s0 + i) * 64 + lane;
            gl_lds16(at + sl * 8, &As[buf][sl * 8]);
        }
    };
    auto loadB = [&](int c) {
        if (c < 288) {
            int octk = c * 8 + oct;
            int ic = octk / 9, ky = octk - ic * 9;
            int off = ic * 3136 + ky * 56;
#pragma unroll
            for (int i = 0; i < 4; ++i) {
                u32x4u v = *(const u32x4u*)(h1 + bsrc[i] + off);
                bR[4 * i + 0] = v[0]; bR[4 * i + 1] = v[1];
                bR[4 * i + 2] = v[2]; bR[4 * i + 3] = v[3];
            }
        } else {
            int base = c * 64 + thalf * 32 - 18432;
#pragma unroll
            for (int p = 0; p < 16; ++p) {
                int j2 = base + 2 * p;
                int icA = j2 / 9, kyA = j2 - icA * 9;
                int icB = (j2 + 1) / 9, kyB = (j2 + 1) - icB * 9;
                uint32_t ba = h1[tbase + icA * 3136 + kyA * 56];
                uint32_t bb = h1[tbase + icB * 3136 + kyB * 56];
                bR[p] = ba | (bb << 16);
            }
        }
    };
    auto writeB = [&](int c) {
        if (c < 288) {
#pragma unroll
            for (int i = 0; i < 4; ++i) {
                u32x4a v = {bR[4 * i], bR[4 * i + 1], bR[4 * i + 2], bR[4 * i + 3]};
                *(u32x4a*)(&Bs[bdst[i]]) = v;
            }
        } else {
#pragma unroll
            for (int p = 0; p < 16; ++p)
                *(uint32_t*)(&Bs[tn * C2ROW + thalf * 32 + 2 * p]) = bR[p];
        }
    };

    const int nch = (324 - z + 7) >> 3;   // 41 for z<4, 40 for z>=4
    int c = z;
    issueA(c, 0);
    loadB(c);
    for (int i = 0; i < nch; ++i) {
        const int cur = i & 1;
        const int ccur = c, cnext = c + 8;
        __asm__ volatile("s_waitcnt vmcnt(0)" ::: "memory");
        __syncthreads();                  // A(ccur) landed in As[cur]; prev compute done
        writeB(ccur);
        __syncthreads();                  // Bs ready
        if (i + 1 < nch) { issueA(cnext, cur ^ 1); loadB(cnext); }  // fly across compute
#pragma unroll
        for (int h = 0; h < 2; ++h) {
            short8 af[4], bf[4];
#pragma unroll
            for (int im = 0; im < 4; ++im) {
                int row = wy * 64 + im * 16 + l16;
                int koct = h * 4 + q;
                af[im] = *(const short8*)(&As[cur][(row * 8 + (koct ^ (row & 7))) * 8]);
            }
#pragma unroll
            for (int in = 0; in < 4; ++in)
                bf[in] = *(const short8*)(&Bs[(wx * 64 + in * 16 + l16) * C2ROW + h * 32 + q * 8]);
#pragma unroll
            for (int im = 0; im < 4; ++im)
#pragma unroll
                for (int in = 0; in < 4; ++in)
                    acc[im][in] = __builtin_amdgcn_mfma_f32_16x16x32_bf16(af[im], bf[in], acc[im][in], 0, 0, 0);
        }
        c = cnext;
    }

    // epilogue: accumulate split-K partial into c2
    const int m0 = blockIdx.y * 128;
#pragma unroll
    for (int in = 0; in < 4; ++in) {
        int nn = n0 + wx * 64 + in * 16 + l16;
        int bb = nn / 576, pp = nn % 576;
#pragma unroll
        for (int im = 0; im < 4; ++im) {
#pragma unroll
            for (int r = 0; r < 4; ++r) {
                int oc = m0 + wy * 64 + im * 16 + q * 4 + r;
                atomicAdd(&c2[(bb * 256 + oc) * 576 + pp], acc[im][in][r]);
            }
        }
    }
}

// ---------------- squash primary caps (+ conv2 bias) ----------------
__global__ void squash_caps(const float* __restrict__ c2, const float* __restrict__ bias,
                            float* __restrict__ caps) {
    int idx = blockIdx.x * 256 + threadIdx.x;   // 589824 = 32*32*576
    int b = idx / 18432;
    int rp = idx % 18432;
    int r = rp / 576, p = rp % 576;
    float s[8]; float n2 = 0.f;
#pragma unroll
    for (int d = 0; d < 8; ++d) {
        s[d] = c2[(b * 256 + r * 8 + d) * 576 + p] + bias[r * 8 + d];
        n2 += s[d] * s[d];
    }
    float sc = (n2 / (1.f + n2)) / sqrtf(n2 + 1e-8f);
#pragma unroll
    for (int d = 0; d < 8; ++d)
        caps[idx * 8 + d] = sc * s[d];
}

// ---------------- routing ----------------
// iteration 0: softmax is uniform (1/10) -> G = capsum/10
__global__ __launch_bounds__(64) void capsum0(const float* __restrict__ caps,
                                              float* __restrict__ G) {
    int r = blockIdx.x, b = blockIdx.y;
    const float* cp = caps + (size_t)(b * 32 + r) * 4608;
    int tid = threadIdx.x;
    f32x4 s0 = (f32x4){0.f, 0.f, 0.f, 0.f}, s1 = s0;
    for (int jv = 0; jv < 9; ++jv) {
        const f32x4* qp = (const f32x4*)(cp + (jv * 64 + tid) * 8);
        s0 += qp[0]; s1 += qp[1];
    }
#pragma unroll
    for (int off = 32; off > 0; off >>= 1) {
#pragma unroll
        for (int k = 0; k < 4; ++k) {
            s0[k] += __shfl_down(s0[k], off, 64);
            s1[k] += __shfl_down(s1[k], off, 64);
        }
    }
    if (tid == 0) {
        float g[8] = {s0[0], s0[1], s0[2], s0[3], s1[0], s1[1], s1[2], s1[3]};
        float* gp = G + (size_t)((b * 32 + r) * 10) * 8;
        for (int cc = 0; cc < 10; ++cc)
#pragma unroll
            for (int ii = 0; ii < 8; ++ii) gp[cc * 8 + ii] = g[ii] * 0.1f;
    }
}

// iterations 1,2: fused wv + accumulation
__global__ __launch_bounds__(64) void route_accum(const float* __restrict__ caps,
                                                  const float* __restrict__ W,
                                                  const float* __restrict__ V,
                                                  float* __restrict__ G) {
    int r = blockIdx.x, b = blockIdx.y;
    __shared__ float wv[80];
    __shared__ float red[80][64];
    int tid = threadIdx.x;
    for (int v = tid; v < 80; v += 64) {
        int cc = v >> 3, ii = v & 7;
        float s = 0.f;
#pragma unroll
        for (int o = 0; o < 16; ++o)
            s += W[((r * 10 + cc) * 8 + ii) * 16 + o] * V[(b * 10 + cc) * 16 + o];
        wv[v] = s;
    }
    __syncthreads();
    float g[80];
#pragma unroll
    for (int v = 0; v < 80; ++v) g[v] = 0.f;
    const float* cp = caps + (size_t)(b * 32 + r) * 4608;
    for (int j = 0; j < 9; ++j) {
        int p = j * 64 + tid;
        const f32x4* qp = (const f32x4*)(cp + p * 8);
        f32x4 c0 = qp[0], c1 = qp[1];
        float c8[8];
#pragma unroll
        for (int i = 0; i < 4; ++i) { c8[i] = c0[i]; c8[4 + i] = c1[i]; }
        float a[10]; float m = -1e30f;
#pragma unroll
        for (int cc = 0; cc < 10; ++cc) {
            float t = 0.f;
#pragma unroll
            for (int i = 0; i < 8; ++i) t += c8[i] * wv[cc * 8 + i];
            a[cc] = t; m = fmaxf(m, t);
        }
        float sum = 0.f;
#pragma unroll
        for (int cc = 0; cc < 10; ++cc) { a[cc] = __expf(a[cc] - m); sum += a[cc]; }
        float inv = 1.f / sum;
#pragma unroll
        for (int cc = 0; cc < 10; ++cc) {
            float w = a[cc] * inv;
#pragma unroll
            for (int i = 0; i < 8; ++i) g[cc * 8 + i] += w * c8[i];
        }
    }
#pragma unroll
    for (int v = 0; v < 80; ++v) red[v][tid] = g[v];
    __syncthreads();
    for (int v = tid; v < 80; v += 64) {
        float s = 0.f;
        for (int t = 0; t < 64; ++t) s += red[v][t];
        G[(b * 32 + r) * 80 + v] = s;
    }
}

__global__ __launch_bounds__(160) void sv_kernel(const float* __restrict__ G,
                                                 const float* __restrict__ W,
                                                 float* __restrict__ V,
                                                 float* __restrict__ out, int last) {
    int b = blockIdx.x;
    int c = threadIdx.x / 16, o = threadIdx.x % 16;
    __shared__ float sL[10][16];
    float s = 0.f;
    for (int r = 0; r < 32; ++r) {
        const float* g = G + ((b * 32 + r) * 10 + c) * 8;
        const float* w = W + ((r * 10 + c) * 8) * 16 + o;
#pragma unroll
        for (int i = 0; i < 8; ++i) s += g[i] * w[i * 16];
    }
    sL[c][o] = s;
    __syncthreads();
    float n2 = 0.f;
#pragma unroll
    for (int oo = 0; oo < 16; ++oo) { float t = sL[c][oo]; n2 += t * t; }
    float sc = (n2 / (1.f + n2)) / sqrtf(n2 + 1e-8f);
    float v = sc * s;
    V[(b * 10 + c) * 16 + o] += v;
    if (last) out[(b * 10 + c) * 16 + o] = v;
}

// ---------------- launch ----------------
extern "C" void kernel_launch(void* const* d_in, const int* in_sizes, int n_in,
                              void* d_out, int out_size, void* d_ws, size_t ws_size,
                              hipStream_t stream) {
    const float* x  = (const float*)d_in[0];
    const float* w1 = (const float*)d_in[1];
    const float* b1 = (const float*)d_in[2];
    const float* w2 = (const float*)d_in[3];
    const float* b2 = (const float*)d_in[4];
    const float* rw = (const float*)d_in[5];

    char* ws = (char*)d_ws;
    unsigned short* A1   = (unsigned short*)(ws);                  // 262,144 B
    unsigned short* A2   = (unsigned short*)(ws + 262144);         // 10,616,832 B
    unsigned short* h1   = (unsigned short*)(ws + 10878976);       // 51,380,224 B
    float*          c2   = (float*)(ws + 62259200);                // 18,874,368 B
    float*          caps = (float*)(ws + 81133568);                // 18,874,368 B
    float*          V    = (float*)(ws + 100007936);               // 20,480 B
    float*          G    = (float*)(ws + 100028416);               // 327,680 B

    hipLaunchKernelGGL(cvt_w1, dim3(256), dim3(256), 0, stream, w1, A1);
    hipLaunchKernelGGL(cvt_w2, dim3(20736), dim3(256), 0, stream, w2, A2);
    hipMemsetAsync(c2, 0, 18874368, stream);
    hipLaunchKernelGGL(conv1_gemm, dim3(784, 2), dim3(256), 0, stream, A1, x, b1, h1);
    hipLaunchKernelGGL(conv2_gemm, dim3(144, 2, 8), dim3(256), 0, stream, A2, h1, c2);
    hipLaunchKernelGGL(squash_caps, dim3(2304), dim3(256), 0, stream, c2, b2, caps);
    hipMemsetAsync(V, 0, 5120 * sizeof(float), stream);
    hipLaunchKernelGGL(capsum0, dim3(32, 32), dim3(64), 0, stream, caps, G);
    hipLaunchKernelGGL(sv_kernel, dim3(32), dim3(160), 0, stream, G, rw, V, (float*)d_out, 0);
    for (int it = 1; it < 3; ++it) {
        hipLaunchKernelGGL(route_accum, dim3(32, 32), dim3(64), 0, stream, caps, rw, V, G);
        hipLaunchKernelGGL(sv_kernel, dim3(32), dim3(160), 0, stream, G, rw, V,
                           (float*)d_out, it == 2 ? 1 : 0);
    }
}